// Round 11
// baseline (123.151 us; speedup 1.0000x reference)
//
#include <hip/hip_runtime.h>
#include <hip/hip_bf16.h>

// LocallyConnected2d: B=16, C=32, O=32, H=W=64, K=3x3, pad=1, stride=1.
// out[b,o,h,w] = sum_{c,k} x[b,c,h+dh,w+dw] * weight[o,c,h,w,k]
//
// R11: recombination driven by 5 rounds of evidence:
//  - x-tap VMEM dominates (R5 vs R6: +6 loads/(c,b) = +30us) -> OO=4 halves
//    x instrs; x as bf16 PAIRS {x[w-1],x[w]} (4B loads) + 1 bpermute for the
//    right tap (lane w+1's hi half). Only mask: mr at w=63.
//  - weights: linear global_load_lds staging (R7: kills stride-36B TA cost),
//    read ONCE (BB=16, no batch split). Per-wave private slots, no barriers.
//  - LDS small: 128-thread blocks, 2 waves x 4oo x 2304B = 18.4KB -> 8
//    blocks/CU (R7-R10's 36.9KB gave only 2).
//  - VGPR room: launch_bounds(128,3) caps ~170 (R9 silently spilled at 80).

#define CIN  32
#define OCH  32
#define HH   64
#define WW   64
#define HW   4096
#define BB   16    // all batches per thread -> weight stream not duplicated
#define OO   4     // output channels per thread -> x instrs / 4
#define CC   4     // input channels per block (c-split 8)
#define XWR  66    // padded rows in XWP

typedef float f32x4 __attribute__((ext_vector_type(4), aligned(16)));

typedef const __attribute__((address_space(1))) unsigned int* gptr1_t;
typedef __attribute__((address_space(3))) unsigned int* lptr3_t;

__device__ __forceinline__ void stage16(const void* g, void* l) {
    __builtin_amdgcn_global_load_lds((gptr1_t)(unsigned long long)g,
                                     (lptr3_t)(unsigned int)(unsigned long long)l,
                                     16, 0, 0);
}
__device__ __forceinline__ void stage4(const void* g, void* l) {
    __builtin_amdgcn_global_load_lds((gptr1_t)(unsigned long long)g,
                                     (lptr3_t)(unsigned int)(unsigned long long)l,
                                     4, 0, 0);
}

__device__ __forceinline__ unsigned short f2bf(float f) {
    unsigned u = __float_as_uint(f);
    u += 0x7fffu + ((u >> 16) & 1u);
    return (unsigned short)(u >> 16);
}
__device__ __forceinline__ float bf_lo(unsigned v) { return __uint_as_float(v << 16); }
__device__ __forceinline__ float bf_hi(unsigned v) { return __uint_as_float(v & 0xffff0000u); }

__global__ __launch_bounds__(256)
void zero_out_kernel(float* __restrict__ out, int n4) {
    int i = blockIdx.x * 256 + threadIdx.x;
    if (i < n4) ((f32x4*)out)[i] = (f32x4){0.f, 0.f, 0.f, 0.f};
}

// XWP[b][c][66][64] : u32 = {bf16 x[h][w-1] (lo), bf16 x[h][w] (hi)} for
// row r=h+1; rows 0/65 zero (vertical pad), w=0 left tap zero.
__global__ __launch_bounds__(256)
void xwp_kernel(const float* __restrict__ x, unsigned* __restrict__ xwp) {
    int tid = blockIdx.x * 256 + threadIdx.x;
    const int total = 16 * CIN * XWR * 64;
    if (tid >= total) return;
    const int w  = tid & 63;
    const int r  = (tid >> 6) % XWR;
    const int bc = tid / (XWR * 64);
    const int h  = r - 1;
    float xl = 0.f, xm = 0.f;
    if (h >= 0 && h < HH) {
        const float* row = x + (size_t)bc * HW + (size_t)h * WW;
        xl = (w > 0) ? row[w - 1] : 0.f;
        xm = row[w];
    }
    xwp[tid] = (unsigned)f2bf(xl) | ((unsigned)f2bf(xm) << 16);
}

template<bool XWOK>
__global__ __launch_bounds__(128, 3)
void lc2d_kernel(const float* __restrict__ x, const float* __restrict__ wt,
                 const unsigned* __restrict__ xwp, float* __restrict__ out) {
    // per-wave private weight slots: [ty][oo*576 floats] = 2*9216B = 18432B
    __shared__ float smem[2][OO * 576];
    const int w  = threadIdx.x;                 // lane == w
    const int ty = threadIdx.y;                 // 0..1
    const int h  = blockIdx.x * 2 + ty;
    const int o0 = blockIdx.y * OO;
    const int c0 = blockIdx.z * CC;

    const float mr = (w < WW - 1) ? 1.f : 0.f;  // only mask needed (pair-XW)
    const int   ldn = ((w < 63) ? w + 1 : 63) << 2;

    // fallback path helpers (XWOK=false only)
    const float mt = (h > 0) ? 1.f : 0.f, mb = (h < HH - 1) ? 1.f : 0.f;
    const float ml = (w > 0) ? 1.f : 0.f;
    const int iht = (h > 0) ? h - 1 : 0, ihb = (h < HH - 1) ? h + 1 : HH - 1;
    const int cl = (w > 0) ? w - 1 : 0, cr = (w < WW - 1) ? w + 1 : WW - 1;

    float acc[OO][BB];
#pragma unroll
    for (int oo = 0; oo < OO; ++oo)
#pragma unroll
        for (int b = 0; b < BB; ++b) acc[oo][b] = 0.f;

    for (int c = 0; c < CC; ++c) {
        const int cc = c0 + c;

        // stage 4 weight rows (2304B contiguous each) linearly into this
        // wave's private LDS slot
#pragma unroll
        for (int oo = 0; oo < OO; ++oo) {
            const char* src = (const char*)wt
                + ((size_t)(o0 + oo) * CIN + cc) * ((size_t)HW * 36)
                + (size_t)h * 2304;
            float* lb = &smem[ty][oo * 576];
            stage16(src + (size_t)w * 16,        lb);
            stage16(src + 1024 + (size_t)w * 16, lb + 256);
            stage4 (src + 2048 + (size_t)w * 4,  lb + 512);
        }
        __builtin_amdgcn_s_waitcnt(0);

        // per-lane weights (stride-9 dwords: 2-way bank alias = free)
        float wk[OO][9];
#pragma unroll
        for (int oo = 0; oo < OO; ++oo) {
            const float* wp = &smem[ty][oo * 576] + w * 9;
#pragma unroll
            for (int k = 0; k < 9; ++k) wk[oo][k] = wp[k];
            if (XWOK) {
                wk[oo][2] *= mr; wk[oo][5] *= mr; wk[oo][8] *= mr;
            } else {
                wk[oo][0] *= mt * ml; wk[oo][1] *= mt; wk[oo][2] *= mt * mr;
                wk[oo][3] *= ml;                        wk[oo][5] *= mr;
                wk[oo][6] *= mb * ml; wk[oo][7] *= mb; wk[oo][8] *= mb * mr;
            }
        }

        int xwi = (cc * (XWR * 64)) + h * 64 + w;   // b=0; +CIN*XWR*64 per b
#pragma unroll
        for (int b = 0; b < BB; ++b) {
            float t0, t1, t2, t3, t4, t5, t6, t7, t8;
            if (XWOK) {
                const unsigned r0 = xwp[xwi];
                const unsigned r1 = xwp[xwi + 64];
                const unsigned r2 = xwp[xwi + 128];
                const unsigned q0 = __builtin_amdgcn_ds_bpermute(ldn, (int)r0);
                const unsigned q1 = __builtin_amdgcn_ds_bpermute(ldn, (int)r1);
                const unsigned q2 = __builtin_amdgcn_ds_bpermute(ldn, (int)r2);
                t0 = bf_lo(r0); t1 = bf_hi(r0); t2 = bf_hi(q0);
                t3 = bf_lo(r1); t4 = bf_hi(r1); t5 = bf_hi(q1);
                t6 = bf_lo(r2); t7 = bf_hi(r2); t8 = bf_hi(q2);
                xwi += CIN * XWR * 64;
            } else {
                const float* xp = x + ((size_t)b * CIN + cc) * HW;
                const float* r0 = xp + iht * WW;
                const float* r1 = xp + h * WW;
                const float* r2 = xp + ihb * WW;
                t0 = r0[cl]; t1 = r0[w]; t2 = r0[cr];
                t3 = r1[cl]; t4 = r1[w]; t5 = r1[cr];
                t6 = r2[cl]; t7 = r2[w]; t8 = r2[cr];
            }
#pragma unroll
            for (int oo = 0; oo < OO; ++oo) {
                float a = acc[oo][b];
                a = fmaf(t0, wk[oo][0], a); a = fmaf(t1, wk[oo][1], a);
                a = fmaf(t2, wk[oo][2], a); a = fmaf(t3, wk[oo][3], a);
                a = fmaf(t4, wk[oo][4], a); a = fmaf(t5, wk[oo][5], a);
                a = fmaf(t6, wk[oo][6], a); a = fmaf(t7, wk[oo][7], a);
                a = fmaf(t8, wk[oo][8], a);
                acc[oo][b] = a;
            }
        }
    }

#pragma unroll
    for (int b = 0; b < BB; ++b)
#pragma unroll
        for (int oo = 0; oo < OO; ++oo)
            atomicAdd(out + (((size_t)b * OCH + (o0 + oo)) * HH + h) * WW + w,
                      acc[oo][b]);
}

extern "C" void kernel_launch(void* const* d_in, const int* in_sizes, int n_in,
                              void* d_out, int out_size, void* d_ws, size_t ws_size,
                              hipStream_t stream) {
    const float* x  = (const float*)d_in[0];
    const float* wt = (const float*)d_in[1];
    float* out = (float*)d_out;

    const int n4 = out_size / 4;
    zero_out_kernel<<<(n4 + 255) / 256, 256, 0, stream>>>(out, n4);

    const size_t ws_need = (size_t)16 * CIN * XWR * 64 * 4;   // 8.65 MB
    dim3 block(64, 2);
    dim3 grid(HH / 2, OCH / OO, 8);   // 32 x 8 x 8 = 2048 blocks

    if (ws_size >= ws_need) {
        unsigned* xwp = (unsigned*)d_ws;
        const int total = 16 * CIN * XWR * 64;
        xwp_kernel<<<(total + 255) / 256, 256, 0, stream>>>(x, xwp);
        lc2d_kernel<true><<<grid, block, 0, stream>>>(x, wt, xwp, out);
    } else {
        lc2d_kernel<false><<<grid, block, 0, stream>>>(x, wt, (const unsigned*)d_ws, out);
    }
}

// Round 12
// 108.375 us; speedup vs baseline: 1.1363x; 1.1363x over previous
//
#include <hip/hip_runtime.h>
#include <hip/hip_bf16.h>

// LocallyConnected2d: B=16, C=32, O=32, H=W=64, K=3x3, pad=1, stride=1.
// out[b,o,h,w] = sum_{c,k} x[b,c,h+dh,w+dw] * weight[o,c,h,w,k]
//
// R12: no-DS, no-stage, no-duplication. Ledger from R5 (best 57us): bperms
// ~30us DS + weight-dup ~11.5us were the rocks; staging rounds (R7-R11)
// all lost to per-wave drain serialization.
//  - x: bf16 3-tap window prepass XW[b][c][66][64] (pre-padded -> no masks,
//    no bperms; 3 x 8B loads per (c,b)).
//  - weights: direct strided f32x4 loads (R5-proven), BB=16 -> each weight
//    element read by exactly one thread, once.
//  - OO=2 -> regs ~75 (no spill); CC=4, cg=8 -> 2048 blocks = 8 blocks/CU.
//  - no LDS, no barriers; 8 f32 atomic addends per output (commutative).

#define CIN  32
#define OCH  32
#define HH   64
#define WW   64
#define HW   4096
#define BB   16    // all batches per thread -> weight stream read once
#define OO   2     // output channels per thread
#define CC   4     // input channels per block (c-split 8)
#define XWR  66    // padded rows in XW

typedef float f32x4 __attribute__((ext_vector_type(4), aligned(4)));
typedef float f32x4a __attribute__((ext_vector_type(4), aligned(16)));
typedef unsigned int u32x2 __attribute__((ext_vector_type(2), aligned(8)));

__device__ __forceinline__ unsigned short f2bf(float f) {
    unsigned u = __float_as_uint(f);
    u += 0x7fffu + ((u >> 16) & 1u);
    return (unsigned short)(u >> 16);
}
__device__ __forceinline__ float bf_lo(unsigned v) { return __uint_as_float(v << 16); }
__device__ __forceinline__ float bf_hi(unsigned v) { return __uint_as_float(v & 0xffff0000u); }

__global__ __launch_bounds__(256)
void zero_out_kernel(float* __restrict__ out, int n4) {
    int i = blockIdx.x * 256 + threadIdx.x;
    if (i < n4) ((f32x4a*)out)[i] = (f32x4a){0.f, 0.f, 0.f, 0.f};
}

// XW[b][c][66][64] : u32x2{ lo: bf16 x[w-1] | bf16 x[w]<<16, hi: bf16 x[w+1] }
// for row r = h+1; rows 0/65 zero (vertical pad), w edges zero.
__global__ __launch_bounds__(256)
void xwin_kernel(const float* __restrict__ x, u32x2* __restrict__ xw) {
    int tid = blockIdx.x * 256 + threadIdx.x;
    const int total = 16 * CIN * XWR * 64;
    if (tid >= total) return;
    const int w  = tid & 63;
    const int r  = (tid >> 6) % XWR;
    const int bc = tid / (XWR * 64);
    const int h  = r - 1;
    float xl = 0.f, xm = 0.f, xr = 0.f;
    if (h >= 0 && h < HH) {
        const float* row = x + (size_t)bc * HW + (size_t)h * WW;
        xl = (w > 0)      ? row[w - 1] : 0.f;
        xm = row[w];
        xr = (w < WW - 1) ? row[w + 1] : 0.f;
    }
    u32x2 v;
    v.x = (unsigned)f2bf(xl) | ((unsigned)f2bf(xm) << 16);
    v.y = (unsigned)f2bf(xr);
    xw[tid] = v;
}

template<bool XWOK>
__global__ __launch_bounds__(256)
void lc2d_kernel(const float* __restrict__ x, const float* __restrict__ wt,
                 const u32x2* __restrict__ xw, float* __restrict__ out) {
    const int w  = threadIdx.x;                 // lane == w
    const int h  = blockIdx.x * 4 + threadIdx.y;
    const int o0 = blockIdx.y * OO;
    const int c0 = blockIdx.z * CC;

    // fallback-only edge handling (XWOK path needs none: XW is pre-padded)
    const float mt = (h > 0) ? 1.f : 0.f, mb = (h < HH - 1) ? 1.f : 0.f;
    const float ml = (w > 0) ? 1.f : 0.f, mr = (w < WW - 1) ? 1.f : 0.f;
    const int iht = (h > 0) ? h - 1 : 0, ihb = (h < HH - 1) ? h + 1 : HH - 1;
    const int cl = (w > 0) ? w - 1 : 0, cr = (w < WW - 1) ? w + 1 : WW - 1;

    float acc[OO][BB];
#pragma unroll
    for (int oo = 0; oo < OO; ++oo)
#pragma unroll
        for (int b = 0; b < BB; ++b) acc[oo][b] = 0.f;

    for (int c = 0; c < CC; ++c) {
        const int cc = c0 + c;

        // direct strided weight loads (36B lane stride; R5-proven pattern)
        const float* wpa = wt + (((size_t)o0 * CIN + cc) * HW
                                 + (size_t)h * WW + w) * 9;
        const float* wpb = wpa + (size_t)CIN * HW * 9;
        f32x4 a03 = *(const f32x4*)(wpa);
        f32x4 a47 = *(const f32x4*)(wpa + 4);
        float a8  = wpa[8];
        f32x4 b03 = *(const f32x4*)(wpb);
        f32x4 b47 = *(const f32x4*)(wpb + 4);
        float b8  = wpb[8];

        float wa0 = a03.x, wa1 = a03.y, wa2 = a03.z, wa3 = a03.w, wa4 = a47.x,
              wa5 = a47.y, wa6 = a47.z, wa7 = a47.w, wa8 = a8;
        float wb0 = b03.x, wb1 = b03.y, wb2 = b03.z, wb3 = b03.w, wb4 = b47.x,
              wb5 = b47.y, wb6 = b47.z, wb7 = b47.w, wb8 = b8;
        if (!XWOK) {
            wa0 *= mt * ml; wa1 *= mt; wa2 *= mt * mr;
            wa3 *= ml;                  wa5 *= mr;
            wa6 *= mb * ml; wa7 *= mb; wa8 *= mb * mr;
            wb0 *= mt * ml; wb1 *= mt; wb2 *= mt * mr;
            wb3 *= ml;                  wb5 *= mr;
            wb6 *= mb * ml; wb7 *= mb; wb8 *= mb * mr;
        }

        int xwi = cc * (XWR * 64) + h * 64 + w;   // b=0; += CIN*XWR*64 per b
#pragma unroll
        for (int b = 0; b < BB; ++b) {
            float t0, t1, t2, t3, t4, t5, t6, t7, t8;
            if (XWOK) {
                const u32x2 r0 = xw[xwi];
                const u32x2 r1 = xw[xwi + 64];
                const u32x2 r2 = xw[xwi + 128];
                t0 = bf_lo(r0.x); t1 = bf_hi(r0.x); t2 = bf_lo(r0.y);
                t3 = bf_lo(r1.x); t4 = bf_hi(r1.x); t5 = bf_lo(r1.y);
                t6 = bf_lo(r2.x); t7 = bf_hi(r2.x); t8 = bf_lo(r2.y);
                xwi += CIN * XWR * 64;
            } else {
                const float* xp = x + ((size_t)b * CIN + cc) * HW;
                const float* r0 = xp + iht * WW;
                const float* r1 = xp + h * WW;
                const float* r2 = xp + ihb * WW;
                t0 = r0[cl]; t1 = r0[w]; t2 = r0[cr];
                t3 = r1[cl]; t4 = r1[w]; t5 = r1[cr];
                t6 = r2[cl]; t7 = r2[w]; t8 = r2[cr];
            }
            float a = acc[0][b];
            a = fmaf(t0, wa0, a); a = fmaf(t1, wa1, a); a = fmaf(t2, wa2, a);
            a = fmaf(t3, wa3, a); a = fmaf(t4, wa4, a); a = fmaf(t5, wa5, a);
            a = fmaf(t6, wa6, a); a = fmaf(t7, wa7, a); a = fmaf(t8, wa8, a);
            acc[0][b] = a;

            float q = acc[1][b];
            q = fmaf(t0, wb0, q); q = fmaf(t1, wb1, q); q = fmaf(t2, wb2, q);
            q = fmaf(t3, wb3, q); q = fmaf(t4, wb4, q); q = fmaf(t5, wb5, q);
            q = fmaf(t6, wb6, q); q = fmaf(t7, wb7, q); q = fmaf(t8, wb8, q);
            acc[1][b] = q;
        }
    }

#pragma unroll
    for (int b = 0; b < BB; ++b)
#pragma unroll
        for (int oo = 0; oo < OO; ++oo)
            atomicAdd(out + (((size_t)b * OCH + (o0 + oo)) * HH + h) * WW + w,
                      acc[oo][b]);
}

extern "C" void kernel_launch(void* const* d_in, const int* in_sizes, int n_in,
                              void* d_out, int out_size, void* d_ws, size_t ws_size,
                              hipStream_t stream) {
    const float* x  = (const float*)d_in[0];
    const float* wt = (const float*)d_in[1];
    float* out = (float*)d_out;

    const int n4 = out_size / 4;
    zero_out_kernel<<<(n4 + 255) / 256, 256, 0, stream>>>(out, n4);

    const size_t ws_need = (size_t)16 * CIN * XWR * 64 * 8;   // 17.3 MB
    dim3 block(64, 4);
    dim3 grid(HH / 4, OCH / OO, 8);   // 16 x 16 x 8 = 2048 blocks

    if (ws_size >= ws_need) {
        u32x2* xw = (u32x2*)d_ws;
        const int total = 16 * CIN * XWR * 64;
        xwin_kernel<<<(total + 255) / 256, 256, 0, stream>>>(x, xw);
        lc2d_kernel<true><<<grid, block, 0, stream>>>(x, wt, xw, out);
    } else {
        lc2d_kernel<false><<<grid, block, 0, stream>>>(x, wt, (const u32x2*)d_ws, out);
    }
}